// Round 7
// baseline (210.592 us; speedup 1.0000x reference)
//
#include <hip/hip_runtime.h>
#include <stdint.h>

// TypedLinear: out[i] = W[types[i]] @ x[i] + b[types[i]]
// N=65536, IN=OUT=256, T=8, fp32 in/out. bf16-MFMA grouped-GEMM, PER-WAVE tiles.
// This rev: zero barriers, zero LDS in the gemm. Each wave independently owns
// 16 same-type rows (global bucket) x 256 cols:
//   - A fragments loaded straight from x into registers (32B/lane, coalesced)
//   - B fragments streamed from packed Wp (L2-resident) in 8-frag halves
//   - no __syncthreads anywhere -> loads hoist freely, waves self-overlap
// Dispatches: memset(32B) + fused pack/bucket + plan + gemm.

#define NROWS 65536
#define NTYPES 8
#define KDIM 256
#define ODIM 256
#define GM 16                       // rows per wave-group
#define MAX_GROUPS (NROWS / GM + NTYPES)   // 4104 worst case
#define NBLK ((MAX_GROUPS + 3) / 4)        // 4 waves per block

typedef __attribute__((ext_vector_type(8))) short short8;
typedef __attribute__((ext_vector_type(4))) float f32x4;

__device__ __forceinline__ unsigned short f2bf(float f) {
    // round-to-nearest-even fp32 -> bf16
    unsigned int u = __float_as_uint(f);
    u += 0x7fffu + ((u >> 16) & 1u);
    return (unsigned short)(u >> 16);
}

// ---------------- fused prep + bucket ----------------
// blocks [0,256): pack W fp32 -> bf16 in MFMA-fragment order, fully coalesced:
//   Wp[((t*16+f)*8+q)*512 + l*8 + e] = bf16(W[t][f*16+(l&15)][q*32+(l>>4)*8+e])
// blocks [256,512): per-type index lists via LDS histogram -> 8 global atomics.
// cnt pre-zeroed by hipMemsetAsync.
__global__ void prep_bucket_kernel(const float* __restrict__ W,
                                   unsigned short* __restrict__ Wp,
                                   const int* __restrict__ types,
                                   int* __restrict__ cnt,
                                   int* __restrict__ idx) {
    const int b = blockIdx.x;
    if (b < 256) {
        const int gid = b * 256 + threadIdx.x;      // 0..65535
        const int R   = gid >> 5;                   // W row: t*256 + r
        const int c32 = gid & 31;                   // 8-float chunk of the row
        const int t  = R >> 8;
        const int r  = R & 255;
        const int f  = r >> 4;
        const int rr = r & 15;
        const int q  = c32 >> 2;
        const int l  = (c32 & 3) * 16 + rr;
        const float* src = W + (size_t)R * KDIM + c32 * 8;
        const float4 v0 = *(const float4*)src;
        const float4 v1 = *(const float4*)(src + 4);
        ushort4 p0, p1;
        p0.x = f2bf(v0.x); p0.y = f2bf(v0.y); p0.z = f2bf(v0.z); p0.w = f2bf(v0.w);
        p1.x = f2bf(v1.x); p1.y = f2bf(v1.y); p1.z = f2bf(v1.z); p1.w = f2bf(v1.w);
        ushort4* dst = (ushort4*)(Wp + (size_t)(((t * 16 + f) * 8 + q) * 512 + l * 8));
        dst[0] = p0; dst[1] = p1;
    } else {
        __shared__ int h[NTYPES];
        __shared__ int base[NTYPES];
        int i = (b - 256) * 256 + threadIdx.x;
        if (threadIdx.x < NTYPES) h[threadIdx.x] = 0;
        __syncthreads();
        int t = types[i];
        int r = atomicAdd(&h[t], 1);
        __syncthreads();
        if (threadIdx.x < NTYPES)
            base[threadIdx.x] = atomicAdd(&cnt[threadIdx.x], h[threadIdx.x]);
        __syncthreads();
        idx[t * NROWS + base[t] + r] = i;
    }
}

// ---------------- plan: flat 16-row group table ----------------
// 1 block. plan[g] = { (m0<<4)|t , count } for each live group, -1 for the rest.
__global__ void plan_kernel(const int* __restrict__ cnt, int2* __restrict__ plan) {
    __shared__ int start[NTYPES + 1];
    if (threadIdx.x == 0) {
        int acc = 0;
        for (int t = 0; t < NTYPES; ++t) {
            start[t] = acc;
            acc += (cnt[t] + GM - 1) / GM;
        }
        start[NTYPES] = acc;
    }
    __syncthreads();
    #pragma unroll
    for (int t = 0; t < NTYPES; ++t) {
        const int s = start[t], e = start[t + 1], c = cnt[t];
        for (int i = s + (int)threadIdx.x; i < e; i += 256)
            plan[i] = make_int2((((i - s) * GM) << 4) | t, c);
    }
    for (int i = start[NTYPES] + (int)threadIdx.x; i < MAX_GROUPS; i += 256)
        plan[i] = make_int2(-1, 0);
}

// ---------------- per-wave grouped GEMM: no LDS, no barriers ----------------
// wave gw = blockIdx*4 + waveid handles plan[gw]: 16 same-type rows x 256 cols.
// A: lane (lr,lq) reads x[idx[m0+lr]][q*32+lq*8 .. +8] fp32 -> short8.
// B: packed Wp record (t, colfrag f, q) at Wp[t*64K + (f*8+q)*512 + lane*8].
// D: col = f*16 + (lane&15), row-in-group = (lane>>4)*4 + reg.
__global__ __launch_bounds__(256, 4)
void gemm_kernel(const float* __restrict__ x,
                 const float* __restrict__ bias,
                 const unsigned short* __restrict__ Wp,
                 const int2* __restrict__ plan,
                 const int* __restrict__ idx,
                 float* __restrict__ out) {
    const int gw = blockIdx.x * 4 + (threadIdx.x >> 6);
    const int2 pe = plan[gw];
    if (pe.x < 0) return;              // wave-uniform exit; no barriers exist
    const int t = pe.x & 15;
    const int m0 = pe.x >> 4;
    const int count = pe.y;

    const int lane = threadIdx.x & 63;
    const int lr = lane & 15;
    const int lq = lane >> 4;

    // A row for this lane (clamped duplicate for the tail group)
    const int gr = m0 + lr;
    const int xrow = idx[t * NROWS + (gr < count ? gr : count - 1)];
    const float* xbase = x + (size_t)xrow * KDIM + lq * 8;

    // B record base for this lane
    const unsigned short* wb = Wp + (size_t)t * (16 * 8 * 512) + lane * 8;

    f32x4 acc[16] = {};

    #pragma unroll
    for (int q = 0; q < 8; ++q) {
        const float4 a0 = *(const float4*)(xbase + q * 32);
        const float4 a1 = *(const float4*)(xbase + q * 32 + 4);
        short8 af;
        af[0] = (short)f2bf(a0.x); af[1] = (short)f2bf(a0.y);
        af[2] = (short)f2bf(a0.z); af[3] = (short)f2bf(a0.w);
        af[4] = (short)f2bf(a1.x); af[5] = (short)f2bf(a1.y);
        af[6] = (short)f2bf(a1.z); af[7] = (short)f2bf(a1.w);
        #pragma unroll
        for (int h = 0; h < 2; ++h) {
            short8 bf[8];
            #pragma unroll
            for (int j = 0; j < 8; ++j)
                bf[j] = *(const short8*)(wb + (size_t)(h * 8 + j) * 4096 + q * 512);
            #pragma unroll
            for (int j = 0; j < 8; ++j)
                acc[h * 8 + j] = __builtin_amdgcn_mfma_f32_16x16x32_bf16(
                    af, bf[j], acc[h * 8 + j], 0, 0, 0);
        }
    }

    // ---- epilogue: rows lq*4+r of the group, cols f*16+lr
    int rowid[4];
    bool ok[4];
    #pragma unroll
    for (int r = 0; r < 4; ++r) {
        const int rr = m0 + lq * 4 + r;
        ok[r] = rr < count;
        rowid[r] = idx[t * NROWS + (rr < count ? rr : count - 1)];
    }
    #pragma unroll
    for (int f = 0; f < 16; ++f) {
        const float bv = bias[t * ODIM + f * 16 + lr];
        #pragma unroll
        for (int r = 0; r < 4; ++r) {
            if (ok[r])
                out[(size_t)rowid[r] * ODIM + f * 16 + lr] = acc[f][r] + bv;
        }
    }
}

extern "C" void kernel_launch(void* const* d_in, const int* in_sizes, int n_in,
                              void* d_out, int out_size, void* d_ws, size_t ws_size,
                              hipStream_t stream) {
    const float* x     = (const float*)d_in[0];
    const int*   types = (const int*)d_in[1];
    const float* W     = (const float*)d_in[2];
    const float* b     = (const float*)d_in[3];
    float* out = (float*)d_out;

    // ws layout: [0,32) cnt | [256, 256+MAX_GROUPS*8) plan | [64K, +2MB) idx | then 1MB Wp
    char* ws = (char*)d_ws;
    int* cnt = (int*)ws;
    int2* plan = (int2*)(ws + 256);
    int* idx = (int*)(ws + 65536);
    unsigned short* Wp = (unsigned short*)(ws + 65536 + (size_t)NTYPES * NROWS * sizeof(int));

    hipMemsetAsync(cnt, 0, NTYPES * sizeof(int), stream);
    prep_bucket_kernel<<<512, 256, 0, stream>>>(W, Wp, types, cnt, idx);
    plan_kernel<<<1, 256, 0, stream>>>(cnt, plan);
    gemm_kernel<<<NBLK, 256, 0, stream>>>(x, b, Wp, plan, idx, out);
}

// Round 8
// 146.130 us; speedup vs baseline: 1.4411x; 1.4411x over previous
//
#include <hip/hip_runtime.h>
#include <stdint.h>

// TypedLinear: out[i] = W[types[i]] @ x[i] + b[types[i]]
// N=65536, IN=OUT=256, T=8, fp32 in/out. bf16-MFMA grouped-GEMM via type bucketing.
// This rev = round-2 structure (best, 43.6us) + TRANSPOSED B-packing so the
// MFMA D columns are lane-consecutive: frag f holds W-rows {lr*16+f} instead of
// {f*16+lr}. Epilogue becomes float4 stores (4x fewer store instrs / line
// touches), bias becomes one float4 load. Everything else unchanged.

#define NROWS 65536
#define NTYPES 8
#define KDIM 256
#define ODIM 256
#define BM 64
#define MAX_TILES (NROWS / BM + NTYPES - 1)   // 1031 worst case

typedef __attribute__((ext_vector_type(8))) short short8;
typedef __attribute__((ext_vector_type(4))) float f32x4;

__device__ __forceinline__ unsigned short f2bf(float f) {
    // round-to-nearest-even fp32 -> bf16
    unsigned int u = __float_as_uint(f);
    u += 0x7fffu + ((u >> 16) & 1u);
    return (unsigned short)(u >> 16);
}

// ---------------- fused prep + bucket ----------------
// blocks [0,256): pack W fp32 -> bf16 in MFMA-fragment order, TRANSPOSED frag
// mapping: W row r of type t goes to frag f = r&15, lane-slot rr = r>>4, i.e.
//   Wp[((t*16+f)*8+q)*512 + l*8 + e] = bf16(W[t][(l&15)*16+f][q*32+(l>>4)*8+e])
// so D col for (frag f, lane lr) = lr*16+f -> consecutive across a wave's frags.
// blocks [256,512): per-type index lists via LDS histogram -> 8 global atomics.
// cnt pre-zeroed by hipMemsetAsync.
__global__ void prep_bucket_kernel(const float* __restrict__ W,
                                   unsigned short* __restrict__ Wp,
                                   const int* __restrict__ types,
                                   int* __restrict__ cnt,
                                   int* __restrict__ idx) {
    const int b = blockIdx.x;
    if (b < 256) {
        const int gid = b * 256 + threadIdx.x;      // 0..65535
        const int R   = gid >> 5;                   // W row: t*256 + r
        const int c32 = gid & 31;                   // which 8-float chunk of the row
        const int t  = R >> 8;
        const int r  = R & 255;
        const int f  = r & 15;                      // TRANSPOSED: frag = low nibble
        const int rr = r >> 4;                      //             slot = high nibble
        const int q  = c32 >> 2;
        const int l  = (c32 & 3) * 16 + rr;
        const float* src = W + (size_t)R * KDIM + c32 * 8;
        const float4 v0 = *(const float4*)src;
        const float4 v1 = *(const float4*)(src + 4);
        ushort4 p0, p1;
        p0.x = f2bf(v0.x); p0.y = f2bf(v0.y); p0.z = f2bf(v0.z); p0.w = f2bf(v0.w);
        p1.x = f2bf(v1.x); p1.y = f2bf(v1.y); p1.z = f2bf(v1.z); p1.w = f2bf(v1.w);
        ushort4* dst = (ushort4*)(Wp + (size_t)(((t * 16 + f) * 8 + q) * 512 + l * 8));
        dst[0] = p0; dst[1] = p1;
    } else {
        __shared__ int h[NTYPES];
        __shared__ int base[NTYPES];
        int i = (b - 256) * 256 + threadIdx.x;
        if (threadIdx.x < NTYPES) h[threadIdx.x] = 0;
        __syncthreads();
        int t = types[i];
        int r = atomicAdd(&h[t], 1);
        __syncthreads();
        if (threadIdx.x < NTYPES)
            base[threadIdx.x] = atomicAdd(&cnt[threadIdx.x], h[threadIdx.x]);
        __syncthreads();
        idx[t * NROWS + base[t] + r] = i;
    }
}

// ---------------- grouped GEMM ----------------
// grid (MAX_TILES): flat m-tile -> (type, m0). 256 threads = 4 waves, each wave
// owns 64 output cols {lr*16 + wave*4 + j}; all share the 64-row A tile.
// As: [64 rows][256 k] bf16 (32 KB), 16B-chunk XOR swizzle c' = c ^ (row&7).
// B frags: coalesced short8 loads from packed Wp (L2-resident, 1 MB total).
__global__ __launch_bounds__(256, 4)
void gemm_kernel(const float* __restrict__ x,
                 const float* __restrict__ bias,
                 const unsigned short* __restrict__ Wp,
                 const int* __restrict__ cnt,
                 const int* __restrict__ idx,
                 float* __restrict__ out) {
    // ---- flat tile id -> (type t, tile base m0); uniform scalar work
    const int bid = blockIdx.x;
    int t = -1, m0 = 0, count = 0, accum = 0;
    #pragma unroll
    for (int i = 0; i < NTYPES; ++i) {
        int c = cnt[i];
        int ntile = (c + BM - 1) / BM;
        if (t < 0 && bid < accum + ntile) { t = i; m0 = (bid - accum) * BM; count = c; }
        accum += ntile;
    }
    if (t < 0) return;                 // only a handful of tail blocks

    __shared__ unsigned short As[BM * KDIM];    // 32 KB, swizzled
    __shared__ int idx_s[BM];
    char* AsB = (char*)As;

    const int tid = threadIdx.x;
    const int wave = tid >> 6;       // 0..3
    const int lane = tid & 63;
    const int lr = lane & 15;
    const int lq = lane >> 4;

    // ---- bias: one float4 per thread, cols lr*16 + wave*4 + 0..3 (16B aligned)
    const float4 bv = *(const float4*)(bias + t * ODIM + lr * 16 + wave * 4);

    const int srow = tid >> 4;       // 0..15
    const int sc   = tid & 15;

    // ---- stage A: 64 rows x 256 fp32 -> bf16 LDS, one burst, one barrier.
    #pragma unroll
    for (int p = 0; p < 4; ++p) {
        const int row = p * 16 + srow;
        const int gr = m0 + row;
        const int xr = idx[t * NROWS + (gr < count ? gr : count - 1)];
        if (sc == 0) idx_s[row] = xr;
        const float* xs = x + (size_t)xr * KDIM;
        #pragma unroll
        for (int s = 0; s < 4; ++s) {
            const int slot = s * 16 + sc;            // float4 slot 0..63
            const float4 v = *(const float4*)(xs + slot * 4);
            ushort4 pk;
            pk.x = f2bf(v.x); pk.y = f2bf(v.y); pk.z = f2bf(v.z); pk.w = f2bf(v.w);
            const int c = slot >> 1;                 // 16B chunk 0..31
            *(ushort4*)(AsB + row * 512 + (c ^ (row & 7)) * 16 + (slot & 1) * 8) = pk;
        }
    }
    __syncthreads();

    const unsigned short* Wpt = Wp + (size_t)t * 16 * 8 * 512;   // type base

    f32x4 acc[4][4] = {};

    // ---- compute: 8 k32-chunks x 16 MFMAs; B frags streamed from L2.
    #pragma unroll
    for (int q = 0; q < 8; ++q) {
        short8 bf[4], af[4];
        #pragma unroll
        for (int j = 0; j < 4; ++j)
            bf[j] = *(const short8*)(Wpt + ((size_t)((wave * 4 + j) * 8 + q)) * 512
                                         + lane * 8);
        #pragma unroll
        for (int i = 0; i < 4; ++i) {
            const int row = i * 16 + lr;
            af[i] = *(const short8*)(AsB + row * 512
                                         + (((q << 2) + lq) ^ (row & 7)) * 16);
        }
        #pragma unroll
        for (int i = 0; i < 4; ++i)
            #pragma unroll
            for (int j = 0; j < 4; ++j)
                acc[i][j] = __builtin_amdgcn_mfma_f32_16x16x32_bf16(
                    af[i], bf[j], acc[i][j], 0, 0, 0);
    }

    // ---- epilogue: row = i*16 + lq*4 + r; cols lr*16 + wave*4 + 0..3 -> float4
    #pragma unroll
    for (int i = 0; i < 4; ++i) {
        #pragma unroll
        for (int r = 0; r < 4; ++r) {
            const int lm = i * 16 + lq * 4 + r;
            const int gr = m0 + lm;
            if (gr < count) {
                const size_t orow = (size_t)idx_s[lm] * ODIM;
                float4 v;
                v.x = acc[i][0][r] + bv.x;
                v.y = acc[i][1][r] + bv.y;
                v.z = acc[i][2][r] + bv.z;
                v.w = acc[i][3][r] + bv.w;
                *(float4*)(out + orow + lr * 16 + wave * 4) = v;
            }
        }
    }
}

extern "C" void kernel_launch(void* const* d_in, const int* in_sizes, int n_in,
                              void* d_out, int out_size, void* d_ws, size_t ws_size,
                              hipStream_t stream) {
    const float* x     = (const float*)d_in[0];
    const int*   types = (const int*)d_in[1];
    const float* W     = (const float*)d_in[2];
    const float* b     = (const float*)d_in[3];
    float* out = (float*)d_out;

    // ws layout: [0,32) cnt | [1024, 1024+2MB) idx | then 1MB packed bf16 W
    char* ws = (char*)d_ws;
    int* cnt = (int*)ws;
    int* idx = (int*)(ws + 1024);
    unsigned short* Wp = (unsigned short*)(ws + 1024 + (size_t)NTYPES * NROWS * sizeof(int));

    hipMemsetAsync(cnt, 0, NTYPES * sizeof(int), stream);
    prep_bucket_kernel<<<512, 256, 0, stream>>>(W, Wp, types, cnt, idx);
    gemm_kernel<<<MAX_TILES, 256, 0, stream>>>(x, b, Wp, cnt, idx, out);
}